// Round 1
// baseline (498.017 us; speedup 1.0000x reference)
//
#include <hip/hip_runtime.h>
#include <hip/hip_bf16.h>
#include <cstdint>

// Problem constants: W [N=1024, M=8192], x [B=8192, N=1024], b [1024]
// idx = 0..4095 (quantized cols), idx_comp = 4096..8191 (continuous cols)
//
// cont path = x @ (Wc@Wc^T) = x @ G, G [1024,1024] symmetric.
// DAG (all bf16 MFMA):
//   L1: W-quant+transpose -> Wq,WqT | Wc cast -> Wcb | amax_x
//   L2: prep_x (xq, xbf)
//   L3: G = Wcb@Wcb^T (64 blocks, 128x128) | gemm1: Hexp = xq@Wq (512 blocks,
//       256x256) -- both in one 576-block, 512-thread launch using the
//       pipelined counted-vmcnt schedule (T2 swizzle + T3/T4 + T5).
//   L4: quant_h in place
//   L5: gemm2: out = relu(Hq@Wq^T + xbf@G + b), 256x128 tiles, 256 blocks.

using bf16x8 = __attribute__((ext_vector_type(8))) __bf16;
using f32x4  = __attribute__((ext_vector_type(4))) float;

typedef const __attribute__((address_space(1))) void g_void;
typedef __attribute__((address_space(3))) void l_void;

__device__ __forceinline__ void gload16(const void* g, void* l) {
  __builtin_amdgcn_global_load_lds((g_void*)g, (l_void*)l, 16, 0, 0);
}

__device__ __forceinline__ ushort f2bf(float f) {
  union { float f; unsigned u; } c; c.f = f;
  unsigned r = c.u + 0x7FFFu + ((c.u >> 16) & 1u);  // RNE truncate
  return (ushort)(r >> 16);
}
__device__ __forceinline__ float bf2f(ushort u) {
  union { unsigned u; float f; } c; c.u = ((unsigned)u) << 16;
  return c.f;
}

template <int N>
__device__ __forceinline__ void wait_vmcnt() {
  static_assert(N == 0 || N == 2 || N == 3 || N == 4 || N == 6 || N == 8, "");
  if constexpr (N == 0) asm volatile("s_waitcnt vmcnt(0)" ::: "memory");
  else if constexpr (N == 2) asm volatile("s_waitcnt vmcnt(2)" ::: "memory");
  else if constexpr (N == 3) asm volatile("s_waitcnt vmcnt(3)" ::: "memory");
  else if constexpr (N == 4) asm volatile("s_waitcnt vmcnt(4)" ::: "memory");
  else if constexpr (N == 6) asm volatile("s_waitcnt vmcnt(6)" ::: "memory");
  else if constexpr (N == 8) asm volatile("s_waitcnt vmcnt(8)" ::: "memory");
}

// ============ L1: W quant+transpose (blocks <1024) | Wc cast (<5120) | amax_x ============
__global__ void prep_wa_kernel(const float* __restrict__ W,
                               const float4* __restrict__ x,
                               ushort* __restrict__ Wq,
                               ushort* __restrict__ WqT,
                               ushort* __restrict__ Wcb,
                               unsigned* __restrict__ amax_bits) {
  const int bidx = blockIdx.x;
  const int tid = threadIdx.x;

  if (bidx < 1024) {
    __shared__ __align__(16) ushort tile[64][72];
    const int rt = bidx >> 6;
    const int ct = bidx & 63;
    const int r0 = rt * 64, c0 = ct * 64;
    const int e = tid & 31;
    const int hw = tid >> 5;
    #pragma unroll
    for (int it = 0; it < 16; ++it) {
      const int g = it * 8 + hw;
      const int row = g >> 1;
      const int cg = (g & 1) * 32;
      const float w = W[(size_t)(r0 + row) * 8192 + c0 + cg + e];
      float aw = fabsf(w);
      float m = aw;
      #pragma unroll
      for (int d = 1; d <= 16; d <<= 1) m = fmaxf(m, __shfl_xor(m, d));
      int idx = (aw == m) ? e : 32;
      #pragma unroll
      for (int d = 1; d <= 16; d <<= 1) idx = min(idx, __shfl_xor(idx, d));
      const int i1 = idx;
      float a2 = (e == i1) ? -1.f : aw;
      float m2 = a2;
      #pragma unroll
      for (int d = 1; d <= 16; d <<= 1) m2 = fmaxf(m2, __shfl_xor(m2, d));
      int idx2 = (a2 == m2) ? e : 32;
      #pragma unroll
      for (int d = 1; d <= 16; d <<= 1) idx2 = min(idx2, __shfl_xor(idx2, d));
      const int i2 = idx2;

      const float scale = fmaxf(m, 1e-8f);
      const float nb = w / scale;
      float q;
      if (e == i1 || e == i2) {
        q = rintf(nb * 7.f) / 7.f;
      } else {
        float s = (nb > 0.f) ? 1.f : ((nb < 0.f) ? -1.f : 0.f);
        q = s * ((fabsf(nb) > 0.66f) ? 1.f : (1.f / 3.f));
      }
      const ushort qb = f2bf(q * scale);
      Wq[(size_t)(r0 + row) * 4096 + c0 + cg + e] = qb;
      tile[cg + e][row] = qb;
    }
    __syncthreads();
    const int c = tid >> 2;
    const int q4 = (tid & 3) * 16;
    uint4 v0 = *(const uint4*)&tile[c][q4];
    uint4 v1 = *(const uint4*)&tile[c][q4 + 8];
    *(uint4*)(WqT + (size_t)(c0 + c) * 1024 + r0 + q4) = v0;
    *(uint4*)(WqT + (size_t)(c0 + c) * 1024 + r0 + q4 + 8) = v1;
  } else if (bidx < 5120) {
    const int u = (bidx - 1024) * 256 + tid;
    const int row = u >> 10;
    const int c4 = u & 1023;
    float4 v = *(const float4*)(W + (size_t)row * 8192 + 4096 + c4 * 4);
    ushort4 o;
    o.x = f2bf(v.x); o.y = f2bf(v.y); o.z = f2bf(v.z); o.w = f2bf(v.w);
    *(ushort4*)(Wcb + (size_t)row * 4096 + c4 * 4) = o;
  } else {
    float m = 0.f;
    const int base = (bidx - 5120) * 256 + tid;
    const int stride = 2048 * 256;
    for (int i = base; i < 8192 * 1024 / 4; i += stride) {
      float4 v = x[i];
      m = fmaxf(m, fmaxf(fmaxf(fabsf(v.x), fabsf(v.y)),
                         fmaxf(fabsf(v.z), fabsf(v.w))));
    }
    #pragma unroll
    for (int off = 32; off > 0; off >>= 1) m = fmaxf(m, __shfl_down(m, off));
    __shared__ float wm[4];
    int lane = tid & 63, wave = tid >> 6;
    if (lane == 0) wm[wave] = m;
    __syncthreads();
    if (tid == 0) {
      float r = fmaxf(fmaxf(wm[0], wm[1]), fmaxf(wm[2], wm[3]));
      atomicMax(amax_bits, __float_as_uint(r));
    }
  }
}

// ============ L2: prep_x (xq fake-quant + xbf cast), 16B stores ============
__global__ void prep_x_kernel(const float4* __restrict__ x,
                              const unsigned* __restrict__ amax_bits,
                              uint4* __restrict__ xq, uint4* __restrict__ xbf) {
  const float amax = fmaxf(__uint_as_float(*amax_bits), 1e-8f);
  const float scale = 127.f / amax;
  const int base = blockIdx.x * 256 + threadIdx.x;
  const int stride = 2048 * 256;
  const int n8 = 8192 * 1024 / 8;
  for (int i = base; i < n8; i += stride) {
    float4 a = x[i * 2], b = x[i * 2 + 1];
    float v[8] = {a.x, a.y, a.z, a.w, b.x, b.y, b.z, b.w};
    unsigned qw[4], bw[4];
    #pragma unroll
    for (int j = 0; j < 4; ++j) {
      float q0 = fminf(fmaxf(rintf(v[2 * j] * scale), -128.f), 127.f) / scale;
      float q1 = fminf(fmaxf(rintf(v[2 * j + 1] * scale), -128.f), 127.f) / scale;
      qw[j] = (unsigned)f2bf(q0) | ((unsigned)f2bf(q1) << 16);
      bw[j] = (unsigned)f2bf(v[2 * j]) | ((unsigned)f2bf(v[2 * j + 1]) << 16);
    }
    xq[i] = make_uint4(qw[0], qw[1], qw[2], qw[3]);
    xbf[i] = make_uint4(bw[0], bw[1], bw[2], bw[3]);
  }
}

// ============ Pipelined GEMM core (T2 swizzle + T3/T4 counted vmcnt + T5) ============
// LDS per operand: [2 buf][2 kk][rows][32] bf16, rows = FI*64 (A) / FJ*32 (B).
// Group g = (tile t = g>>1, kk = g&1); slot = (buf = t&1, kk). Groups are issued
// in order; 3 groups in flight (prologue 0..2, phase p issues p+3, end-of-phase
// waits vmcnt(2*OPG) => group p+1 complete before phase p+1 reads it. Slot g is
// overwritten by group g+4, issued at phase g+1, i.e. after the barrier that
// follows all reads of group g. Tail: vmcnt(OPG) then vmcnt(0) on last 2 waits.
template <int FI, int FJ, int OPG, class STAGE>
__device__ __forceinline__ void pipe2(ushort (&As)[32768], ushort (&Bs)[32768],
                                      const int NG, STAGE&& stage,
                                      f32x4 (&acc)[FI][FJ],
                                      const int aoff0, const int boff0) {
  constexpr int ASTR = FI * 2048;   // ushorts per (buf,kk) A block
  constexpr int BSTR = FJ * 1024;   // ushorts per (buf,kk) B block
  stage(0); stage(1); stage(2);
  wait_vmcnt<2 * OPG>();
  __builtin_amdgcn_s_barrier();
  auto phase = [&](int p, int buf, int kk) {
    __builtin_amdgcn_sched_barrier(0);  // no reads hoisted above prior barrier
    const ushort* Ab = &As[buf * (2 * ASTR) + kk * ASTR];
    const ushort* Bb = &Bs[buf * (2 * BSTR) + kk * BSTR];
    bf16x8 af[FI]; bf16x8 bfr[FJ];
    #pragma unroll
    for (int i = 0; i < FI; ++i)
      af[i] = *(const bf16x8*)(Ab + aoff0 + i * 512);
    #pragma unroll
    for (int j = 0; j < FJ; ++j)
      bfr[j] = *(const bf16x8*)(Bb + boff0 + j * 512);
    if (p + 3 < NG) stage(p + 3);
    __builtin_amdgcn_s_barrier();
    __builtin_amdgcn_s_setprio(1);
    #pragma unroll
    for (int i = 0; i < FI; ++i)
      #pragma unroll
      for (int j = 0; j < FJ; ++j)
        acc[i][j] = __builtin_amdgcn_mfma_f32_16x16x32_bf16(af[i], bfr[j],
                                                            acc[i][j], 0, 0, 0);
    __builtin_amdgcn_s_setprio(0);
    if (p < NG - 3) wait_vmcnt<2 * OPG>();
    else if (p == NG - 3) wait_vmcnt<OPG>();
    else if (p == NG - 2) wait_vmcnt<0>();
    __builtin_amdgcn_s_barrier();
  };
  for (int p0 = 0; p0 < NG; p0 += 4) {
    phase(p0 + 0, 0, 0);
    phase(p0 + 1, 0, 1);
    phase(p0 + 2, 1, 0);
    phase(p0 + 3, 1, 1);
  }
}

// ============ L3: G-GEMM (blocks <64, 128x128) | gemm1 (512 blocks, 256x256) ============
__global__ __launch_bounds__(512, 2) void gemm1_kernel(
    const ushort* __restrict__ Wcb, ushort* __restrict__ G,
    const ushort* __restrict__ Aq, const ushort* __restrict__ BT,
    ushort* __restrict__ Hexp, unsigned* __restrict__ amax_bits) {
  __shared__ __align__(16) ushort As[32768];
  __shared__ __align__(16) ushort Bs[32768];
  __shared__ float wred[8];
  const int tid = threadIdx.x;
  const int lane = tid & 63, wave = tid >> 6;
  const int wm = wave >> 1, wn = wave & 1;          // 4M x 2N wave grid
  const int l15 = lane & 15, quad = (lane >> 4) & 3;
  // chunk swizzle: logical chunk c at (row,c') with c' = c ^ ((row>>1)&3)
  const int sel = (quad ^ ((l15 >> 1) & 3)) * 8;     // read-side (ushorts)
  const int scs = ((tid & 3) ^ ((tid >> 3) & 3)) * 8;// stage-side (ushorts)
  const int rsrc = tid >> 2;                         // stage row within op-block
  const int l = blockIdx.x;

  if (l < 64) {
    // ---- G path: 128x128 tiles, K=4096, FI=2 FJ=4, 1 A-op + 1 B-op per group ----
    const int by = l >> 3, bx = l & 7;
    const ushort* aB = Wcb + (size_t)(by * 128 + rsrc) * 4096 + scs;
    const ushort* bB = Wcb + (size_t)(bx * 128 + rsrc) * 4096 + scs;
    f32x4 acc[2][4];
    #pragma unroll
    for (int i = 0; i < 2; ++i)
      #pragma unroll
      for (int j = 0; j < 4; ++j) acc[i][j] = (f32x4){0.f, 0.f, 0.f, 0.f};
    const int aoff0 = (wm * 32 + l15) * 32 + sel;
    const int boff0 = (wn * 64 + l15) * 32 + sel;
    auto stage = [&](int g) {
      const int t = g >> 1, kk = g & 1, buf = t & 1;
      const int koff = t * 64 + kk * 32;
      gload16(aB + koff, &As[buf * 8192 + kk * 4096 + tid * 8]);
      gload16(bB + koff, &Bs[buf * 8192 + kk * 4096 + tid * 8]);
    };
    pipe2<2, 4, 2>(As, Bs, 128, stage, acc, aoff0, boff0);
    const int row0 = by * 128 + wm * 32 + quad * 4;
    const int col0 = bx * 128 + wn * 64 + l15;
    #pragma unroll
    for (int i = 0; i < 2; ++i)
      #pragma unroll
      for (int j = 0; j < 4; ++j)
        #pragma unroll
        for (int r = 0; r < 4; ++r)
          G[(size_t)(row0 + i * 16 + r) * 1024 + (col0 + j * 16)] =
              f2bf(acc[i][j][r]);
    return;
  }

  // ---- gemm1: Hexp[8192,4096] = xq @ Wq, 256x256 tiles, FI=4 FJ=8 ----
  const int lg = l - 64;                    // 0..511; 64%8==0 keeps XCD map
  const int wgid = (lg & 7) * 64 + (lg >> 3);
  const int by = wgid >> 4, bx = wgid & 15;

  const ushort* aB = Aq + (size_t)(by * 256 + rsrc) * 1024 + scs;
  const ushort* bB = BT + (size_t)(bx * 256 + rsrc) * 1024 + scs;
  f32x4 acc[4][8];
  #pragma unroll
  for (int i = 0; i < 4; ++i)
    #pragma unroll
    for (int j = 0; j < 8; ++j) acc[i][j] = (f32x4){0.f, 0.f, 0.f, 0.f};
  const int aoff0 = (wm * 64 + l15) * 32 + sel;
  const int boff0 = (wn * 128 + l15) * 32 + sel;
  auto stage = [&](int g) {
    const int t = g >> 1, kk = g & 1, buf = t & 1;
    const int koff = t * 64 + kk * 32;
    ushort* ad = &As[buf * 16384 + kk * 8192 + tid * 8];
    gload16(aB + koff, ad);
    gload16(aB + 131072 + koff, ad + 4096);          // +128 rows * 1024
    ushort* bd = &Bs[buf * 16384 + kk * 8192 + tid * 8];
    gload16(bB + koff, bd);
    gload16(bB + 131072 + koff, bd + 4096);
  };
  pipe2<4, 8, 4>(As, Bs, 32, stage, acc, aoff0, boff0);

  const int row0 = by * 256 + wm * 64 + quad * 4;
  const int col0 = bx * 256 + wn * 128 + l15;
  float lmax = 0.f;
  #pragma unroll
  for (int i = 0; i < 4; ++i)
    #pragma unroll
    for (int j = 0; j < 8; ++j)
      #pragma unroll
      for (int r = 0; r < 4; ++r) {
        float v = acc[i][j][r];
        lmax = fmaxf(lmax, fabsf(v));
        Hexp[(size_t)(row0 + i * 16 + r) * 4096 + (col0 + j * 16)] = f2bf(v);
      }
  #pragma unroll
  for (int off = 32; off > 0; off >>= 1)
    lmax = fmaxf(lmax, __shfl_down(lmax, off));
  if (lane == 0) wred[wave] = lmax;
  __syncthreads();
  if (tid == 0) {
    float m = wred[0];
    #pragma unroll
    for (int i = 1; i < 8; ++i) m = fmaxf(m, wred[i]);
    atomicMax(amax_bits, __float_as_uint(m));
  }
}

// ---------------- quantize Hexp [8192,4096] in place (16B accesses) ----------------
__global__ void quant_h_kernel(ushort* __restrict__ H,
                               const unsigned* __restrict__ amax_bits) {
  const float amax = fmaxf(__uint_as_float(*amax_bits), 1e-8f);
  const float scale = 127.f / amax;
  const int n8 = 8192 * 4096 / 8;
  for (int i = blockIdx.x * blockDim.x + threadIdx.x; i < n8;
       i += gridDim.x * blockDim.x) {
    uint4* p = (uint4*)H + i;
    uint4 a = *p;
    unsigned w[4] = {a.x, a.y, a.z, a.w};
    #pragma unroll
    for (int j = 0; j < 4; ++j) {
      float lo = bf2f((ushort)(w[j] & 0xFFFF));
      float hi = bf2f((ushort)(w[j] >> 16));
      lo = fminf(fmaxf(rintf(lo * scale), -128.f), 127.f) / scale;
      hi = fminf(fmaxf(rintf(hi * scale), -128.f), 127.f) / scale;
      w[j] = (unsigned)f2bf(lo) | ((unsigned)f2bf(hi) << 16);
    }
    *p = make_uint4(w[0], w[1], w[2], w[3]);
  }
}

// ---------------- GEMM2: out[8192,1024] = relu(Hq@Wq^T + xbf@G + b) ----------------
// 256x128 tiles (256 blocks), virtual K stream: tiles 0..63 = Hq/Wq (K=4096),
// tiles 64..79 = xbf/G (K=1024). FI=4 FJ=4; 2 A-ops + 1 B-op per group.
__global__ __launch_bounds__(512, 2) void gemm2_kernel(
    const ushort* __restrict__ Hq, const ushort* __restrict__ Wq,
    const ushort* __restrict__ Xb, const ushort* __restrict__ Gm,
    const float* __restrict__ bias, float* __restrict__ out) {
  __shared__ __align__(16) ushort As[32768];
  __shared__ __align__(16) ushort Bs[32768];   // only 16 KB used; LDS 128 KB total
  const int tid = threadIdx.x;
  const int lane = tid & 63, wave = tid >> 6;
  const int wm = wave >> 1, wn = wave & 1;
  const int l15 = lane & 15, quad = (lane >> 4) & 3;
  const int sel = (quad ^ ((l15 >> 1) & 3)) * 8;
  const int scs = ((tid & 3) ^ ((tid >> 3) & 3)) * 8;
  const int rsrc = tid >> 2;

  const int l = blockIdx.x;
  const int wgid = (l & 7) * 32 + (l >> 3);   // bijective XCD swizzle (256%8==0)
  const int by = wgid >> 3, bx = wgid & 7;

  const ushort* a1 = Hq + (size_t)(by * 256 + rsrc) * 4096 + scs;
  const ushort* a2 = Xb + (size_t)(by * 256 + rsrc) * 1024 + scs;
  const ushort* b1 = Wq + (size_t)(bx * 128 + rsrc) * 4096 + scs;
  const ushort* b2 = Gm + (size_t)(bx * 128 + rsrc) * 1024 + scs;

  f32x4 acc[4][4];
  #pragma unroll
  for (int i = 0; i < 4; ++i)
    #pragma unroll
    for (int j = 0; j < 4; ++j) acc[i][j] = (f32x4){0.f, 0.f, 0.f, 0.f};
  const int aoff0 = (wm * 64 + l15) * 32 + sel;
  const int boff0 = (wn * 64 + l15) * 32 + sel;

  auto stage = [&](int g) {
    const int t = g >> 1, kk = g & 1, buf = t & 1;
    ushort* ad = &As[buf * 16384 + kk * 8192 + tid * 8];
    ushort* bd = &Bs[buf * 8192 + kk * 4096 + tid * 8];
    if (t < 64) {
      const int koff = t * 64 + kk * 32;
      gload16(a1 + koff, ad);
      gload16(a1 + (size_t)524288 + koff, ad + 4096);  // +128 rows * 4096
      gload16(b1 + koff, bd);
    } else {
      const int koff = (t - 64) * 64 + kk * 32;
      gload16(a2 + koff, ad);
      gload16(a2 + 131072 + koff, ad + 4096);          // +128 rows * 1024
      gload16(b2 + koff, bd);
    }
  };
  pipe2<4, 4, 3>(As, Bs, 160, stage, acc, aoff0, boff0);

  const int row0 = by * 256 + wm * 64 + quad * 4;
  const int col0 = bx * 128 + wn * 64 + l15;
  #pragma unroll
  for (int i = 0; i < 4; ++i)
    #pragma unroll
    for (int j = 0; j < 4; ++j) {
      float bv = bias[col0 + j * 16];
      #pragma unroll
      for (int r = 0; r < 4; ++r) {
        float v = acc[i][j][r] + bv;
        v = fmaxf(v, 0.f);
        out[(size_t)(row0 + i * 16 + r) * 1024 + (col0 + j * 16)] = v;
      }
    }
}

extern "C" void kernel_launch(void* const* d_in, const int* in_sizes, int n_in,
                              void* d_out, int out_size, void* d_ws, size_t ws_size,
                              hipStream_t stream) {
  (void)in_sizes; (void)n_in; (void)out_size; (void)ws_size;
  const float* x = (const float*)d_in[0];   // [8192,1024]
  const float* W = (const float*)d_in[1];   // [1024,8192]
  const float* b = (const float*)d_in[2];   // [1024]

  char* ws = (char*)d_ws;
  unsigned* scal = (unsigned*)ws;                      // [0]=amax_x, [1]=amax_h
  ushort* xq   = (ushort*)(ws + 256);                  // 16 MB [8192,1024]
  ushort* xbf  = xq   + (size_t)8192 * 1024;           // 16 MB [8192,1024]
  ushort* Wq   = xbf  + (size_t)8192 * 1024;           //  8 MB [1024,4096]
  ushort* WqT  = Wq   + (size_t)1024 * 4096;           //  8 MB [4096,1024]
  ushort* Wcb  = WqT  + (size_t)4096 * 1024;           //  8 MB [1024,4096]
  ushort* G    = Wcb  + (size_t)1024 * 4096;           //  2 MB [1024,1024]
  ushort* Hexp = G    + (size_t)1024 * 1024;           // 64 MB [8192,4096]

  hipMemsetAsync(scal, 0, 256, stream);
  // L1: W-quant+transpose (1024) | Wc-cast (4096) | amax_x (2048)
  prep_wa_kernel<<<7168, 256, 0, stream>>>(W, (const float4*)x, Wq, WqT, Wcb, scal);
  // L2: prep_x (2048)
  prep_x_kernel<<<2048, 256, 0, stream>>>((const float4*)x, scal,
                                          (uint4*)xq, (uint4*)xbf);
  // L3: G-GEMM (blocks 0..63, 128x128) | gemm1 (blocks 64..575, 256x256)
  gemm1_kernel<<<576, 512, 0, stream>>>(Wcb, G, xq, WqT, Hexp, scal + 1);
  quant_h_kernel<<<4096, 256, 0, stream>>>(Hexp, scal + 1);
  // L5: gemm2 (256 blocks, 256x128)
  gemm2_kernel<<<256, 512, 0, stream>>>(Hexp, Wq, xbf, G, b, (float*)d_out);
}